// Round 1
// baseline (8569.274 us; speedup 1.0000x reference)
//
#include <hip/hip_runtime.h>
#include <hip/hip_bf16.h>

// GraphSAGE 3-layer, N=50000 nodes, E=1.6M edges, D=128 everywhere.
// Baseline: atomic scatter aggregation + fp32 fused dual-GEMM combine.

constexpr int N_NODES = 50000;
constexpr int N_EDGES = 1600000;
constexpr int D = 128;
constexpr int NPB = 8;  // nodes per block in combine kernel

// ---------------- fill (zero) kernel: graph-capture-safe memset ----------
__global__ void fill_zero(float* __restrict__ p, size_t n4) {
    size_t i = (size_t)blockIdx.x * blockDim.x + threadIdx.x;
    if (i < n4) {
        ((float4*)p)[i] = make_float4(0.f, 0.f, 0.f, 0.f);
    }
}

// ---------------- degree ------------------------------------------------
__global__ void deg_kernel(const int* __restrict__ dst, float* __restrict__ deg, int n_edges) {
    int e = blockIdx.x * blockDim.x + threadIdx.x;
    if (e < n_edges) atomicAdd(&deg[dst[e]], 1.0f);
}

__global__ void inv_deg_kernel(float* __restrict__ deg, int n) {
    int i = blockIdx.x * blockDim.x + threadIdx.x;
    if (i < n) deg[i] = 1.0f / fmaxf(deg[i], 1.0f);
}

// ---------------- edge scatter: neigh[dst] += h[src] --------------------
// 32 threads per edge, float4 per thread -> 512B row per edge, coalesced.
__global__ void scatter_kernel(const float* __restrict__ h,
                               const int* __restrict__ src,
                               const int* __restrict__ dst,
                               float* __restrict__ neigh, int n_edges) {
    size_t gid = (size_t)blockIdx.x * blockDim.x + threadIdx.x;
    size_t total = (size_t)n_edges * 32;
    if (gid >= total) return;
    int e = (int)(gid >> 5);
    int c = (int)(gid & 31);
    int s = src[e];
    int d = dst[e];
    const float4 v = *(const float4*)(h + (size_t)s * D + c * 4);
    float* p = neigh + (size_t)d * D + c * 4;
    atomicAdd(p + 0, v.x);
    atomicAdd(p + 1, v.y);
    atomicAdd(p + 2, v.z);
    atomicAdd(p + 3, v.w);
}

// ---------------- combine: out = h@Ws^T + b + (neigh*inv_deg)@Wn^T ------
// One block = NPB nodes x 128 cols. Thread j computes column j for NPB rows.
// Weight rows stream from L2 (128KB/block, 6250 blocks -> ~800MB/layer).
__global__ __launch_bounds__(128) void combine_kernel(
        const float* __restrict__ h_in, const float* __restrict__ neigh,
        const float* __restrict__ inv_deg,
        const float* __restrict__ Ws, const float* __restrict__ Wn,
        const float* __restrict__ b, float* __restrict__ out,
        int n_nodes, int do_relu) {
    const int j = threadIdx.x;          // 0..127 output column
    const int n0 = blockIdx.x * NPB;

    __shared__ float hs[NPB][D];
    __shared__ float ns[NPB][D];

    #pragma unroll
    for (int m = 0; m < NPB; ++m) {
        int n = n0 + m;
        if (n < n_nodes) {
            hs[m][j] = h_in[(size_t)n * D + j];
            ns[m][j] = neigh[(size_t)n * D + j] * inv_deg[n];
        } else {
            hs[m][j] = 0.f;
            ns[m][j] = 0.f;
        }
    }
    __syncthreads();

    float acc[NPB];
    const float bj = b[j];
    #pragma unroll
    for (int m = 0; m < NPB; ++m) acc[m] = bj;

    const float4* wsr = (const float4*)(Ws + (size_t)j * D);
    const float4* wnr = (const float4*)(Wn + (size_t)j * D);

    #pragma unroll 4
    for (int k4 = 0; k4 < D / 4; ++k4) {
        float4 w_s = wsr[k4];
        float4 w_n = wnr[k4];
        int k = k4 * 4;
        #pragma unroll
        for (int m = 0; m < NPB; ++m) {
            float a = acc[m];
            a += hs[m][k + 0] * w_s.x + ns[m][k + 0] * w_n.x;
            a += hs[m][k + 1] * w_s.y + ns[m][k + 1] * w_n.y;
            a += hs[m][k + 2] * w_s.z + ns[m][k + 2] * w_n.z;
            a += hs[m][k + 3] * w_s.w + ns[m][k + 3] * w_n.w;
            acc[m] = a;
        }
    }

    #pragma unroll
    for (int m = 0; m < NPB; ++m) {
        int n = n0 + m;
        if (n < n_nodes) {
            float v = acc[m];
            if (do_relu) v = fmaxf(v, 0.f);
            out[(size_t)n * D + j] = v;
        }
    }
}

extern "C" void kernel_launch(void* const* d_in, const int* in_sizes, int n_in,
                              void* d_out, int out_size, void* d_ws, size_t ws_size,
                              hipStream_t stream) {
    const float* x   = (const float*)d_in[0];
    const int* src   = (const int*)d_in[1];
    const int* dst   = (const int*)d_in[2];
    const float* Wn1 = (const float*)d_in[3];
    const float* Ws1 = (const float*)d_in[4];
    const float* b1  = (const float*)d_in[5];
    const float* Wn2 = (const float*)d_in[6];
    const float* Ws2 = (const float*)d_in[7];
    const float* b2  = (const float*)d_in[8];
    const float* Wn3 = (const float*)d_in[9];
    const float* Ws3 = (const float*)d_in[10];
    const float* b3  = (const float*)d_in[11];
    float* out = (float*)d_out;

    // workspace layout
    float* inv_deg = (float*)d_ws;                       // 50176 floats (padded)
    float* bufA = inv_deg + 50176;                       // N*D
    float* bufB = bufA + (size_t)N_NODES * D;            // N*D

    const size_t nd = (size_t)N_NODES * D;               // 6.4M floats
    const int fill_blk = 256;
    const int fill_grid_nd = (int)((nd / 4 + fill_blk - 1) / fill_blk);
    const int fill_grid_deg = (50176 / 4 + fill_blk - 1) / fill_blk;

    const int scat_blk = 256;
    const int scat_grid = (int)(((size_t)N_EDGES * 32 + scat_blk - 1) / scat_blk);
    const int comb_grid = (N_NODES + NPB - 1) / NPB;

    // degree -> inv_deg
    fill_zero<<<fill_grid_deg, fill_blk, 0, stream>>>(inv_deg, 50176 / 4);
    deg_kernel<<<(N_EDGES + 255) / 256, 256, 0, stream>>>(dst, inv_deg, N_EDGES);
    inv_deg_kernel<<<(N_NODES + 255) / 256, 256, 0, stream>>>(inv_deg, N_NODES);

    // ---- layer 1: x -> bufA (relu) ----
    fill_zero<<<fill_grid_nd, fill_blk, 0, stream>>>(bufA, nd / 4);
    scatter_kernel<<<scat_grid, scat_blk, 0, stream>>>(x, src, dst, bufA, N_EDGES);
    combine_kernel<<<comb_grid, 128, 0, stream>>>(x, bufA, inv_deg, Ws1, Wn1, b1,
                                                  bufA, N_NODES, 1);

    // ---- layer 2: bufA -> bufB (relu) ----
    fill_zero<<<fill_grid_nd, fill_blk, 0, stream>>>(bufB, nd / 4);
    scatter_kernel<<<scat_grid, scat_blk, 0, stream>>>(bufA, src, dst, bufB, N_EDGES);
    combine_kernel<<<comb_grid, 128, 0, stream>>>(bufA, bufB, inv_deg, Ws2, Wn2, b2,
                                                  bufB, N_NODES, 1);

    // ---- layer 3: bufB -> d_out (no relu) ----
    fill_zero<<<fill_grid_nd, fill_blk, 0, stream>>>(bufA, nd / 4);
    scatter_kernel<<<scat_grid, scat_blk, 0, stream>>>(bufB, src, dst, bufA, N_EDGES);
    combine_kernel<<<comb_grid, 128, 0, stream>>>(bufB, bufA, inv_deg, Ws3, Wn3, b3,
                                                  out, N_NODES, 0);
}

// Round 2
// 893.535 us; speedup vs baseline: 9.5903x; 9.5903x over previous
//
#include <hip/hip_runtime.h>

// GraphSAGE 3-layer, N=50000, E=1.6M, D=128.
// R2: CSR-by-dst counting sort (int atomics only) + fused gather/mean/dual-GEMM.

constexpr int N_NODES = 50000;
constexpr int N_EDGES = 1600000;
constexpr int D = 128;
constexpr int NPB = 8;    // nodes per block in fused kernel (50000/8 = 6250 exact)
constexpr int EMAX = 768; // staged edge slots per block (avg 256, Poisson margin)

// ---------------- zero counts + cursor ----------------------------------
__global__ void zero_ints(int* __restrict__ a, int* __restrict__ b, int n) {
    int i = blockIdx.x * blockDim.x + threadIdx.x;
    if (i < n) { a[i] = 0; b[i] = 0; }
}

// ---------------- histogram of dst --------------------------------------
__global__ void hist_kernel(const int* __restrict__ dst, int* __restrict__ counts, int n) {
    int e = blockIdx.x * blockDim.x + threadIdx.x;
    if (e < n) atomicAdd(&counts[dst[e]], 1);
}

// ---------------- exclusive scan (single block) + inv_deg ---------------
__global__ __launch_bounds__(1024) void scan_kernel(const int* __restrict__ counts,
                                                    int* __restrict__ row_ptr,
                                                    float* __restrict__ inv_deg, int n) {
    __shared__ int buf[1024];
    __shared__ int carry;
    const int tid = threadIdx.x;
    if (tid == 0) carry = 0;
    __syncthreads();
    for (int base = 0; base < n; base += 1024) {
        int i = base + tid;
        int v = (i < n) ? counts[i] : 0;
        buf[tid] = v;
        __syncthreads();
        for (int off = 1; off < 1024; off <<= 1) {
            int t = (tid >= off) ? buf[tid - off] : 0;
            __syncthreads();
            buf[tid] += t;
            __syncthreads();
        }
        int incl = buf[tid];
        if (i < n) {
            row_ptr[i] = carry + (incl - v);
            inv_deg[i] = 1.0f / fmaxf((float)v, 1.0f);
        }
        __syncthreads();                 // all carry reads done
        if (tid == 1023) carry += buf[1023];
        __syncthreads();                 // carry update visible next iter
    }
    if (tid == 0) row_ptr[n] = carry;
}

// ---------------- bucket edges by dst ------------------------------------
__global__ void bucket_kernel(const int* __restrict__ src, const int* __restrict__ dst,
                              const int* __restrict__ row_ptr, int* __restrict__ cursor,
                              int* __restrict__ esrc, int n) {
    int e = blockIdx.x * blockDim.x + threadIdx.x;
    if (e < n) {
        int d = dst[e];
        int pos = atomicAdd(&cursor[d], 1);
        esrc[row_ptr[d] + pos] = src[e];
    }
}

// ---------------- transpose 6 weight matrices (128x128) ------------------
__global__ void transpose6(const float* __restrict__ w0, const float* __restrict__ w1,
                           const float* __restrict__ w2, const float* __restrict__ w3,
                           const float* __restrict__ w4, const float* __restrict__ w5,
                           float* __restrict__ outbase) {
    const float* ws[6] = {w0, w1, w2, w3, w4, w5};
    const float* w = ws[blockIdx.y];
    float* o = outbase + (size_t)blockIdx.y * D * D;
    int j = blockIdx.x;      // row of W
    int k = threadIdx.x;     // col of W
    o[k * D + j] = w[j * D + k];   // Wt[k][j] = W[j][k]
}

// ---------------- fused: gather-mean + dual GEMM + bias (+relu) ----------
// out[n][j] = b[j] + sum_k h[n][k]*Ws[j][k] + (mean_neigh[n][k])*Wn[j][k]
// Wst/Wnt are transposed: Wt[k*D+j] = W[j][k] -> coalesced lane loads.
__global__ __launch_bounds__(128) void sage_fused(
        const float* __restrict__ h, const int* __restrict__ esrc,
        const int* __restrict__ row_ptr, const float* __restrict__ inv_deg,
        const float* __restrict__ Wst, const float* __restrict__ Wnt,
        const float* __restrict__ bias, float* __restrict__ out, int do_relu) {
    const int j = threadIdx.x;
    const int n0 = blockIdx.x * NPB;

    __shared__ float hs[NPB][D];
    __shared__ float ns[NPB][D];
    __shared__ int eidx[EMAX];
    __shared__ int rp[NPB + 1];

    if (j <= NPB) rp[j] = row_ptr[min(n0 + j, N_NODES)];
    __syncthreads();
    const int e0 = rp[0];
    const int nE = rp[NPB] - e0;
    const int nStage = (nE < EMAX) ? nE : EMAX;
    for (int t = j; t < nStage; t += 128) eidx[t] = esrc[e0 + t];
    __syncthreads();

    #pragma unroll
    for (int m = 0; m < NPB; ++m) {
        int n = n0 + m;
        if (n >= N_NODES) { hs[m][j] = 0.f; ns[m][j] = 0.f; continue; }
        int r0 = rp[m] - e0, r1 = rp[m + 1] - e0;
        float s0 = 0.f, s1 = 0.f, s2 = 0.f, s3 = 0.f;
        int k = r0;
        for (; k + 4 <= r1; k += 4) {
            int i0 = (k     < nStage) ? eidx[k]     : esrc[e0 + k];
            int i1 = (k + 1 < nStage) ? eidx[k + 1] : esrc[e0 + k + 1];
            int i2 = (k + 2 < nStage) ? eidx[k + 2] : esrc[e0 + k + 2];
            int i3 = (k + 3 < nStage) ? eidx[k + 3] : esrc[e0 + k + 3];
            s0 += h[(size_t)i0 * D + j];
            s1 += h[(size_t)i1 * D + j];
            s2 += h[(size_t)i2 * D + j];
            s3 += h[(size_t)i3 * D + j];
        }
        for (; k < r1; ++k) {
            int i0 = (k < nStage) ? eidx[k] : esrc[e0 + k];
            s0 += h[(size_t)i0 * D + j];
        }
        ns[m][j] = ((s0 + s1) + (s2 + s3)) * inv_deg[n];
        hs[m][j] = h[(size_t)n * D + j];
    }
    __syncthreads();

    float acc[NPB];
    const float bj = bias[j];
    #pragma unroll
    for (int m = 0; m < NPB; ++m) acc[m] = bj;

    #pragma unroll 2
    for (int k = 0; k < D; ++k) {
        const float wsk = Wst[k * D + j];
        const float wnk = Wnt[k * D + j];
        #pragma unroll
        for (int m = 0; m < NPB; ++m)
            acc[m] += hs[m][k] * wsk + ns[m][k] * wnk;
    }

    #pragma unroll
    for (int m = 0; m < NPB; ++m) {
        int n = n0 + m;
        if (n < N_NODES) {
            float v = acc[m];
            if (do_relu) v = fmaxf(v, 0.f);
            out[(size_t)n * D + j] = v;
        }
    }
}

extern "C" void kernel_launch(void* const* d_in, const int* in_sizes, int n_in,
                              void* d_out, int out_size, void* d_ws, size_t ws_size,
                              hipStream_t stream) {
    const float* x   = (const float*)d_in[0];
    const int* src   = (const int*)d_in[1];
    const int* dst   = (const int*)d_in[2];
    const float* Wn1 = (const float*)d_in[3];
    const float* Ws1 = (const float*)d_in[4];
    const float* b1  = (const float*)d_in[5];
    const float* Wn2 = (const float*)d_in[6];
    const float* Ws2 = (const float*)d_in[7];
    const float* b2  = (const float*)d_in[8];
    const float* Wn3 = (const float*)d_in[9];
    const float* Ws3 = (const float*)d_in[10];
    const float* b3  = (const float*)d_in[11];
    float* out = (float*)d_out;

    // ---- workspace layout (floats/ints, 4B units) ----
    char* w = (char*)d_ws;
    float* inv_deg = (float*)w;                 w += 50176 * 4;
    int* counts    = (int*)w;                   w += 50176 * 4;
    int* cursor    = (int*)w;                   w += 50176 * 4;
    int* row_ptr   = (int*)w;                   w += 50432 * 4;
    int* esrc      = (int*)w;                   w += (size_t)N_EDGES * 4;
    float* Wt      = (float*)w;                 w += 6 * D * D * 4;
    float* bufA    = (float*)w;                 // N*D floats

    const float* Wnt1 = Wt + 0 * D * D, *Wst1 = Wt + 1 * D * D;
    const float* Wnt2 = Wt + 2 * D * D, *Wst2 = Wt + 3 * D * D;
    const float* Wnt3 = Wt + 4 * D * D, *Wst3 = Wt + 5 * D * D;

    // ---- build CSR by dst ----
    zero_ints<<<(50176 + 255) / 256, 256, 0, stream>>>(counts, cursor, 50176);
    hist_kernel<<<(N_EDGES + 255) / 256, 256, 0, stream>>>(dst, counts, N_EDGES);
    scan_kernel<<<1, 1024, 0, stream>>>(counts, row_ptr, inv_deg, N_NODES);
    bucket_kernel<<<(N_EDGES + 255) / 256, 256, 0, stream>>>(src, dst, row_ptr, cursor,
                                                             esrc, N_EDGES);
    // ---- transpose weights (order: Wn1,Ws1,Wn2,Ws2,Wn3,Ws3) ----
    transpose6<<<dim3(D, 6), D, 0, stream>>>(Wn1, Ws1, Wn2, Ws2, Wn3, Ws3, Wt);

    const int fgrid = N_NODES / NPB;  // 6250 exact
    // layer 1: x -> out (relu)
    sage_fused<<<fgrid, 128, 0, stream>>>(x, esrc, row_ptr, inv_deg,
                                          Wst1, Wnt1, b1, out, 1);
    // layer 2: out -> bufA (relu)
    sage_fused<<<fgrid, 128, 0, stream>>>(out, esrc, row_ptr, inv_deg,
                                          Wst2, Wnt2, b2, bufA, 1);
    // layer 3: bufA -> out (no relu)
    sage_fused<<<fgrid, 128, 0, stream>>>(bufA, esrc, row_ptr, inv_deg,
                                          Wst3, Wnt3, b3, out, 0);
}

// Round 3
// 843.440 us; speedup vs baseline: 10.1599x; 1.0594x over previous
//
#include <hip/hip_runtime.h>

// GraphSAGE 3-layer, N=50000, E=1.6M, D=128.
// R3: float4 quad-per-node gather + NPB=16 + ds_read_b128 combine + shfl scan.

constexpr int N_NODES = 50000;
constexpr int N_EDGES = 1600000;
constexpr int D = 128;
constexpr int NPB = 16;    // nodes per block (50000/16 = 3125 exact)
constexpr int EMAX = 1024; // staged edge slots (avg 512/block)

// ---------------- zero counts + cursor ----------------------------------
__global__ void zero_ints(int* __restrict__ a, int* __restrict__ b, int n) {
    int i = blockIdx.x * blockDim.x + threadIdx.x;
    if (i < n) { a[i] = 0; b[i] = 0; }
}

// ---------------- histogram of dst --------------------------------------
__global__ void hist_kernel(const int* __restrict__ dst, int* __restrict__ counts, int n) {
    int e = blockIdx.x * blockDim.x + threadIdx.x;
    if (e < n) atomicAdd(&counts[dst[e]], 1);
}

// ---------------- exclusive scan (single block, shfl) + inv_deg ---------
__global__ __launch_bounds__(1024) void scan_kernel(const int* __restrict__ counts,
                                                    int* __restrict__ row_ptr,
                                                    float* __restrict__ inv_deg, int n) {
    __shared__ int wsum[16];
    __shared__ int wpre[16];
    const int tid = threadIdx.x;
    const int lane = tid & 63;
    const int w = tid >> 6;
    int carry = 0;
    for (int base = 0; base < n; base += 1024) {
        int i = base + tid;
        int v = (i < n) ? counts[i] : 0;
        int x = v;
        #pragma unroll
        for (int off = 1; off < 64; off <<= 1) {
            int t = __shfl_up(x, off, 64);
            if (lane >= off) x += t;
        }
        if (lane == 63) wsum[w] = x;
        __syncthreads();
        if (w == 0 && lane < 16) {
            int s = wsum[lane];
            int y = s;
            #pragma unroll
            for (int off = 1; off < 16; off <<= 1) {
                int t = __shfl_up(y, off, 64);
                if (lane >= off) y += t;
            }
            wpre[lane] = y - s;   // exclusive prefix of wave sums
        }
        __syncthreads();
        if (i < n) {
            row_ptr[i] = carry + wpre[w] + (x - v);
            inv_deg[i] = 1.0f / fmaxf((float)v, 1.0f);
        }
        carry += wpre[15] + wsum[15];   // chunk total
        __syncthreads();                // protect wsum/wpre reuse
    }
    if (tid == 0) row_ptr[n] = carry;
}

// ---------------- bucket edges by dst ------------------------------------
__global__ void bucket_kernel(const int* __restrict__ src, const int* __restrict__ dst,
                              const int* __restrict__ row_ptr, int* __restrict__ cursor,
                              int* __restrict__ esrc, int n) {
    int e = blockIdx.x * blockDim.x + threadIdx.x;
    if (e < n) {
        int d = dst[e];
        int pos = atomicAdd(&cursor[d], 1);
        esrc[row_ptr[d] + pos] = src[e];
    }
}

// ---------------- transpose 6 weight matrices (128x128) ------------------
__global__ void transpose6(const float* __restrict__ w0, const float* __restrict__ w1,
                           const float* __restrict__ w2, const float* __restrict__ w3,
                           const float* __restrict__ w4, const float* __restrict__ w5,
                           float* __restrict__ outbase) {
    const float* ws[6] = {w0, w1, w2, w3, w4, w5};
    const float* w = ws[blockIdx.y];
    float* o = outbase + (size_t)blockIdx.y * D * D;
    int j = blockIdx.x;
    int k = threadIdx.x;
    o[k * D + j] = w[j * D + k];
}

// ---------------- fused: gather-mean + dual GEMM + bias (+relu) ----------
__global__ __launch_bounds__(128) void sage_fused(
        const float* __restrict__ h, const int* __restrict__ esrc,
        const int* __restrict__ row_ptr, const float* __restrict__ inv_deg,
        const float* __restrict__ Wst, const float* __restrict__ Wnt,
        const float* __restrict__ bias, float* __restrict__ out, int do_relu) {
    const int j = threadIdx.x;
    const int n0 = blockIdx.x * NPB;

    __shared__ float hs[NPB][D];
    __shared__ float ns[NPB][D];
    __shared__ int eidx[EMAX];
    __shared__ int rp[NPB + 1];

    if (j <= NPB) rp[j] = row_ptr[n0 + j];
    __syncthreads();
    const int e0 = rp[0];
    const int nE = rp[NPB] - e0;
    const bool staged = (nE <= EMAX);
    const int nStage = staged ? nE : 0;
    for (int t = j; t < nStage; t += 128) eidx[t] = esrc[e0 + t];
    __syncthreads();

    const int q = j >> 5;   // quad 0..3 -> one node each per iteration
    const int c = j & 31;   // 16B chunk within the 512B row

    #pragma unroll
    for (int it = 0; it < NPB / 4; ++it) {
        const int m = it * 4 + q;
        const int n = n0 + m;
        const int r0 = rp[m] - e0, r1 = rp[m + 1] - e0;
        float4 a0 = {0.f, 0.f, 0.f, 0.f}, a1 = {0.f, 0.f, 0.f, 0.f};
        int k = r0;
        if (staged) {
            for (; k + 4 <= r1; k += 4) {
                int i0 = eidx[k], i1 = eidx[k + 1], i2 = eidx[k + 2], i3 = eidx[k + 3];
                float4 v0 = *(const float4*)(h + (size_t)i0 * D + c * 4);
                float4 v1 = *(const float4*)(h + (size_t)i1 * D + c * 4);
                float4 v2 = *(const float4*)(h + (size_t)i2 * D + c * 4);
                float4 v3 = *(const float4*)(h + (size_t)i3 * D + c * 4);
                a0.x += v0.x; a0.y += v0.y; a0.z += v0.z; a0.w += v0.w;
                a1.x += v1.x; a1.y += v1.y; a1.z += v1.z; a1.w += v1.w;
                a0.x += v2.x; a0.y += v2.y; a0.z += v2.z; a0.w += v2.w;
                a1.x += v3.x; a1.y += v3.y; a1.z += v3.z; a1.w += v3.w;
            }
            for (; k < r1; ++k) {
                int i0 = eidx[k];
                float4 v0 = *(const float4*)(h + (size_t)i0 * D + c * 4);
                a0.x += v0.x; a0.y += v0.y; a0.z += v0.z; a0.w += v0.w;
            }
        } else {
            for (; k + 4 <= r1; k += 4) {
                int i0 = esrc[e0 + k], i1 = esrc[e0 + k + 1];
                int i2 = esrc[e0 + k + 2], i3 = esrc[e0 + k + 3];
                float4 v0 = *(const float4*)(h + (size_t)i0 * D + c * 4);
                float4 v1 = *(const float4*)(h + (size_t)i1 * D + c * 4);
                float4 v2 = *(const float4*)(h + (size_t)i2 * D + c * 4);
                float4 v3 = *(const float4*)(h + (size_t)i3 * D + c * 4);
                a0.x += v0.x; a0.y += v0.y; a0.z += v0.z; a0.w += v0.w;
                a1.x += v1.x; a1.y += v1.y; a1.z += v1.z; a1.w += v1.w;
                a0.x += v2.x; a0.y += v2.y; a0.z += v2.z; a0.w += v2.w;
                a1.x += v3.x; a1.y += v3.y; a1.z += v3.z; a1.w += v3.w;
            }
            for (; k < r1; ++k) {
                int i0 = esrc[e0 + k];
                float4 v0 = *(const float4*)(h + (size_t)i0 * D + c * 4);
                a0.x += v0.x; a0.y += v0.y; a0.z += v0.z; a0.w += v0.w;
            }
        }
        const float idg = inv_deg[n];
        float4 s;
        s.x = (a0.x + a1.x) * idg; s.y = (a0.y + a1.y) * idg;
        s.z = (a0.z + a1.z) * idg; s.w = (a0.w + a1.w) * idg;
        *(float4*)&ns[m][c * 4] = s;
        *(float4*)&hs[m][c * 4] = *(const float4*)(h + (size_t)n * D + c * 4);
    }
    __syncthreads();

    float acc[NPB];
    const float bj = bias[j];
    #pragma unroll
    for (int m = 0; m < NPB; ++m) acc[m] = bj;

    #pragma unroll 2
    for (int k4 = 0; k4 < D / 4; ++k4) {
        float wsv[4], wnv[4];
        #pragma unroll
        for (int kk = 0; kk < 4; ++kk) {
            wsv[kk] = Wst[(k4 * 4 + kk) * D + j];
            wnv[kk] = Wnt[(k4 * 4 + kk) * D + j];
        }
        #pragma unroll
        for (int m = 0; m < NPB; ++m) {
            float4 a = *(const float4*)&hs[m][k4 * 4];
            float4 b = *(const float4*)&ns[m][k4 * 4];
            float t = acc[m];
            t += a.x * wsv[0] + a.y * wsv[1] + a.z * wsv[2] + a.w * wsv[3];
            t += b.x * wnv[0] + b.y * wnv[1] + b.z * wnv[2] + b.w * wnv[3];
            acc[m] = t;
        }
    }

    #pragma unroll
    for (int m = 0; m < NPB; ++m) {
        float v = acc[m];
        if (do_relu) v = fmaxf(v, 0.f);
        out[(size_t)(n0 + m) * D + j] = v;
    }
}

extern "C" void kernel_launch(void* const* d_in, const int* in_sizes, int n_in,
                              void* d_out, int out_size, void* d_ws, size_t ws_size,
                              hipStream_t stream) {
    const float* x   = (const float*)d_in[0];
    const int* src   = (const int*)d_in[1];
    const int* dst   = (const int*)d_in[2];
    const float* Wn1 = (const float*)d_in[3];
    const float* Ws1 = (const float*)d_in[4];
    const float* b1  = (const float*)d_in[5];
    const float* Wn2 = (const float*)d_in[6];
    const float* Ws2 = (const float*)d_in[7];
    const float* b2  = (const float*)d_in[8];
    const float* Wn3 = (const float*)d_in[9];
    const float* Ws3 = (const float*)d_in[10];
    const float* b3  = (const float*)d_in[11];
    float* out = (float*)d_out;

    char* w = (char*)d_ws;
    float* inv_deg = (float*)w;                 w += 50176 * 4;
    int* counts    = (int*)w;                   w += 50176 * 4;
    int* cursor    = (int*)w;                   w += 50176 * 4;
    int* row_ptr   = (int*)w;                   w += 50432 * 4;
    int* esrc      = (int*)w;                   w += (size_t)N_EDGES * 4;
    float* Wt      = (float*)w;                 w += 6 * D * D * 4;
    float* bufA    = (float*)w;                 // N*D floats

    const float* Wnt1 = Wt + 0 * D * D, *Wst1 = Wt + 1 * D * D;
    const float* Wnt2 = Wt + 2 * D * D, *Wst2 = Wt + 3 * D * D;
    const float* Wnt3 = Wt + 4 * D * D, *Wst3 = Wt + 5 * D * D;

    zero_ints<<<(50176 + 255) / 256, 256, 0, stream>>>(counts, cursor, 50176);
    hist_kernel<<<(N_EDGES + 255) / 256, 256, 0, stream>>>(dst, counts, N_EDGES);
    scan_kernel<<<1, 1024, 0, stream>>>(counts, row_ptr, inv_deg, N_NODES);
    bucket_kernel<<<(N_EDGES + 255) / 256, 256, 0, stream>>>(src, dst, row_ptr, cursor,
                                                             esrc, N_EDGES);
    transpose6<<<dim3(D, 6), D, 0, stream>>>(Wn1, Ws1, Wn2, Ws2, Wn3, Ws3, Wt);

    const int fgrid = N_NODES / NPB;  // 3125 exact
    sage_fused<<<fgrid, 128, 0, stream>>>(x, esrc, row_ptr, inv_deg,
                                          Wst1, Wnt1, b1, out, 1);
    sage_fused<<<fgrid, 128, 0, stream>>>(out, esrc, row_ptr, inv_deg,
                                          Wst2, Wnt2, b2, bufA, 1);
    sage_fused<<<fgrid, 128, 0, stream>>>(bufA, esrc, row_ptr, inv_deg,
                                          Wst3, Wnt3, b3, out, 0);
}